// Round 6
// baseline (767.957 us; speedup 1.0000x reference)
//
#include <hip/hip_runtime.h>
#include <hip/hip_bf16.h>

// GCN_large R5b: 1024 thr / 16 waves (4 waves/SIMD), barriered phases with
// 2-D tile splits so all waves stay active. 32x32x16 MFMA main tiles,
// 16x16x32 node-tail. Layouts:
//   Xs [112][136] bf16 : X rows, cols 112..127 zeroed (K-pad)
//   hT [256][136] bf16 : h feature-major [feat][node], cols 112..127 zeroed
//   aB [112][264] bf16 : a node-major [node][feat]
// proj: D[m=node][n=feat] = A(a rows, LDS) x B(W rows, global)
// agg : D[m=feat][n=node] = A(hT rows) x B(Xs rows), K=112 exact
// No proj<->agg overlap within a phase pair (barrier) -> race-free.

#define NODE 112
#define NBATCH 4096
#define SXS 136
#define SHT 136
#define SAB 264
#define HT_OFF (112*SXS)                 // 15232
#define AB_OFF (HT_OFF + 256*SHT)        // 50048
#define SMEM_BYTES ((AB_OFF + 112*SAB)*2)  // 159232 B

typedef float  f4v   __attribute__((ext_vector_type(4)));
typedef float  f16v  __attribute__((ext_vector_type(16)));
typedef __bf16 bf8v  __attribute__((ext_vector_type(8)));
typedef short  s8v   __attribute__((ext_vector_type(8)));
typedef unsigned short ushort_t;

__device__ __forceinline__ ushort_t f2bf(float f) {
  union { float f; unsigned u; } v; v.f = f;
  unsigned r = v.u + 0x7FFFu + ((v.u >> 16) & 1u);   // RNE
  return (ushort_t)(r >> 16);
}
__device__ __forceinline__ float bf2f(ushort_t h) {
  union { unsigned u; float f; } v; v.u = ((unsigned)h) << 16; return v.f;
}
// packed f32x2 -> bf16x2 via hardware cvt (v_cvt_pk_bf16_f32)
__device__ __forceinline__ unsigned pk2(float a, float b) {
  __hip_bfloat162 h = __float22bfloat162_rn(make_float2(a, b));
  unsigned u;
  __builtin_memcpy(&u, &h, 4);
  return u;
}
__device__ __forceinline__ bf8v ld_frag(const ushort_t* p) {
  s8v t = *(const s8v*)p;
  return __builtin_bit_cast(bf8v, t);
}
#define MFMA32(a,b,c) __builtin_amdgcn_mfma_f32_32x32x16_bf16((a),(b),(c),0,0,0)
#define MFMA16(a,b,c) __builtin_amdgcn_mfma_f32_16x16x32_bf16((a),(b),(c),0,0,0)

// proj: hT[feat][node] = relu(a . W^T + bias). One wave: n-tile `ntile`,
// NMT main 32-node tiles from `mstart`, optional 16-node tail (96..111).
template<int KS, int KC, int SA_, int NMT, bool TAIL>
__device__ __forceinline__ void proj_part(
    const ushort_t* aSrc, const ushort_t* __restrict__ Wg, int WK,
    const float* __restrict__ bias, ushort_t* hDst,
    int ntile, int mstart, int lane)
{
  const int l31 = lane & 31, h32 = lane >> 5;
  const int l15 = lane & 15, q4 = lane >> 4;

  f16v acc[NMT > 0 ? NMT : 1];
  if (NMT > 0) {
    #pragma unroll
    for (int m=0;m<NMT;m++)
      #pragma unroll
      for (int r=0;r<16;r++) acc[m][r] = 0.f;
    const ushort_t* aP = aSrc + (mstart*32 + l31)*SA_ + h32*8;
    const ushort_t* bP = Wg + (ntile*32 + l31)*WK + h32*8;
    #pragma unroll
    for (int ks=0; ks<KS; ks++) {
      bf8v B = ld_frag(bP + ks*16);
      #pragma unroll
      for (int m=0;m<NMT;m++)
        acc[m] = MFMA32(ld_frag(aP + m*32*SA_ + ks*16), B, acc[m]);
    }
  }
  f4v at0, at1;
  if (TAIL) {
    at0 = (f4v){0.f,0.f,0.f,0.f}; at1 = (f4v){0.f,0.f,0.f,0.f};
    const ushort_t* aT  = aSrc + (96 + l15)*SA_ + q4*8;
    const ushort_t* bT0 = Wg + (ntile*32 + l15)*WK + q4*8;
    const ushort_t* bT1 = bT0 + 16*WK;
    #pragma unroll
    for (int kc=0; kc<KC; kc++) {
      bf8v At = ld_frag(aT + kc*32);
      at0 = MFMA16(At, ld_frag(bT0 + kc*32), at0);
      at1 = MFMA16(At, ld_frag(bT1 + kc*32), at1);
    }
  }
  if (NMT > 0) {
    float bv = bias[ntile*32 + l31];
    ushort_t* hrow = hDst + (ntile*32 + l31)*SHT;
    #pragma unroll
    for (int m=0;m<NMT;m++)
      #pragma unroll
      for (int g=0;g<4;g++) {
        float v0=acc[m][4*g+0]+bv; v0=v0>0.f?v0:0.f;
        float v1=acc[m][4*g+1]+bv; v1=v1>0.f?v1:0.f;
        float v2=acc[m][4*g+2]+bv; v2=v2>0.f?v2:0.f;
        float v3=acc[m][4*g+3]+bv; v3=v3>0.f?v3:0.f;
        uint2 pv; pv.x = pk2(v0,v1); pv.y = pk2(v2,v3);
        *(uint2*)(hrow + (mstart+m)*32 + 8*g + 4*h32) = pv;
      }
  }
  if (TAIL) {
    #pragma unroll
    for (int s=0;s<2;s++) {
      const f4v& a = s ? at1 : at0;
      float bv = bias[ntile*32 + s*16 + l15];
      float v0=a[0]+bv; v0=v0>0.f?v0:0.f;
      float v1=a[1]+bv; v1=v1>0.f?v1:0.f;
      float v2=a[2]+bv; v2=v2>0.f?v2:0.f;
      float v3=a[3]+bv; v3=v3>0.f?v3:0.f;
      uint2 pv; pv.x = pk2(v0,v1); pv.y = pk2(v2,v3);
      *(uint2*)(hDst + (ntile*32 + s*16 + l15)*SHT + 96 + 4*q4) = pv;
    }
  }
}

// agg: aB[node][feat] = X . h. One wave: feat-tile `mt`, NNT main node-tiles
// from `nstart`, optional node tail (96..111).
template<int NNT, bool TAIL>
__device__ __forceinline__ void agg_part(
    const ushort_t* hS, const ushort_t* Xs_, ushort_t* aDst,
    int mt, int nstart, int lane)
{
  const int l31 = lane & 31, h32 = lane >> 5;
  const int l15 = lane & 15, q4 = lane >> 4;

  f16v acc[NNT > 0 ? NNT : 1];
  if (NNT > 0) {
    #pragma unroll
    for (int n=0;n<NNT;n++)
      #pragma unroll
      for (int r=0;r<16;r++) acc[n][r] = 0.f;
    const ushort_t* aP = hS + (mt*32 + l31)*SHT + h32*8;
    const ushort_t* bP = Xs_ + (nstart*32 + l31)*SXS + h32*8;
    #pragma unroll
    for (int ks=0; ks<7; ks++) {              // K = 112 exact
      bf8v A = ld_frag(aP + ks*16);
      #pragma unroll
      for (int n=0;n<NNT;n++)
        acc[n] = MFMA32(A, ld_frag(bP + n*32*SXS + ks*16), acc[n]);
    }
  }
  f4v at0, at1;
  if (TAIL) {
    at0 = (f4v){0.f,0.f,0.f,0.f}; at1 = (f4v){0.f,0.f,0.f,0.f};
    const ushort_t* bT  = Xs_ + (96 + l15)*SXS + q4*8;
    const ushort_t* aT0 = hS + (mt*32 + l15)*SHT + q4*8;
    const ushort_t* aT1 = aT0 + 16*SHT;
    #pragma unroll
    for (int kc=0; kc<4; kc++) {              // K padded to 128 (zeros)
      bf8v Bt = ld_frag(bT + kc*32);
      at0 = MFMA16(ld_frag(aT0 + kc*32), Bt, at0);
      at1 = MFMA16(ld_frag(aT1 + kc*32), Bt, at1);
    }
  }
  if (NNT > 0) {
    #pragma unroll
    for (int n=0;n<NNT;n++) {
      ushort_t* arow = aDst + ((nstart+n)*32 + l31)*SAB;
      #pragma unroll
      for (int g=0;g<4;g++) {
        uint2 pv;
        pv.x = pk2(acc[n][4*g+0], acc[n][4*g+1]);
        pv.y = pk2(acc[n][4*g+2], acc[n][4*g+3]);
        *(uint2*)(arow + mt*32 + 8*g + 4*h32) = pv;
      }
    }
  }
  if (TAIL) {
    ushort_t* arow = aDst + (96 + l15)*SAB;
    #pragma unroll
    for (int s=0;s<2;s++) {
      const f4v& a = s ? at1 : at0;
      uint2 pv; pv.x = pk2(a[0],a[1]); pv.y = pk2(a[2],a[3]);
      *(uint2*)(arow + mt*32 + s*16 + 4*q4) = pv;
    }
  }
}

__global__ void prep_weights(const float* __restrict__ W1, const float* __restrict__ W2,
                             const float* __restrict__ W3, const float* __restrict__ W4,
                             ushort_t* __restrict__ o)
{
  int i = blockIdx.x*256 + threadIdx.x;
  if (i < 32768) {                       // W1p [256][128], K zero-padded
    int r = i >> 7, c = i & 127;
    o[i] = (c < NODE) ? f2bf(W1[r*NODE + c]) : (ushort_t)0;
  } else if (i < 98304) {                // W2 [256][256]
    o[i] = f2bf(W2[i - 32768]);
  } else if (i < 131072) {               // W3 [128][256]
    o[i] = f2bf(W3[i - 98304]);
  } else if (i < 139264) {               // W4 [64][128]
    o[i] = f2bf(W4[i - 131072]);
  }
}

__global__ void __launch_bounds__(1024, 4) gcn_kernel(
    const float* __restrict__ x, const ushort_t* __restrict__ wsp,
    const float* __restrict__ b1, const float* __restrict__ b2,
    const float* __restrict__ b3, const float* __restrict__ b4,
    const float* __restrict__ W5, const float* __restrict__ b5,
    const float* __restrict__ Wf, const float* __restrict__ bfc,
    float* __restrict__ out)
{
  extern __shared__ ushort_t smem[];
  ushort_t* Xs = smem;
  ushort_t* hT = smem + HT_OFF;
  ushort_t* aB = smem + AB_OFF;

  const int tid  = threadIdx.x;
  const int w    = tid >> 6;
  const int lane = tid & 63;

  // zero K-pad cols 112..127 of Xs and hT (never overwritten later)
  for (int i = tid; i < 112*4; i += 1024) {
    int r = i >> 2, g = i & 3;
    *(uint2*)(Xs + r*SXS + 112 + g*4) = make_uint2(0u, 0u);
  }
  for (int i = tid; i < 256*4; i += 1024) {
    int r = i >> 2, g = i & 3;
    *(uint2*)(hT + r*SHT + 112 + g*4) = make_uint2(0u, 0u);
  }
  // stage X: fp32 global -> bf16 LDS (b64 packed writes)
  {
    const float4* x4 = (const float4*)(x + (size_t)blockIdx.x * (NODE*NODE));
    for (int i = tid; i < (NODE*NODE/4); i += 1024) {
      float4 v = x4[i];
      int r = i / 28, c4 = (i - r*28) * 4;
      uint2 pv; pv.x = pk2(v.x, v.y); pv.y = pk2(v.z, v.w);
      *(uint2*)(Xs + r*SXS + c4) = pv;
    }
  }
  __syncthreads();

  // p1: F=256, K=112 (tail K=128 via Xs pad); (ntile = w&7, mhalf = w>>3)
  if ((w>>3)==0) proj_part<7,4,SXS,2,false>(Xs, wsp, 128, b1, hT, w&7, 0, lane);
  else           proj_part<7,4,SXS,1,true >(Xs, wsp, 128, b1, hT, w&7, 2, lane);
  __syncthreads();
  // a2: F=256; (ftile = w&7, nhalf = w>>3)
  if ((w>>3)==0) agg_part<2,false>(hT, Xs, aB, w&7, 0, lane);
  else           agg_part<1,true >(hT, Xs, aB, w&7, 2, lane);
  __syncthreads();
  // p2: F=256, K=256
  if ((w>>3)==0) proj_part<16,8,SAB,2,false>(aB, wsp + 32768, 256, b2, hT, w&7, 0, lane);
  else           proj_part<16,8,SAB,1,true >(aB, wsp + 32768, 256, b2, hT, w&7, 2, lane);
  __syncthreads();
  // a3: F=256
  if ((w>>3)==0) agg_part<2,false>(hT, Xs, aB, w&7, 0, lane);
  else           agg_part<1,true >(hT, Xs, aB, w&7, 2, lane);
  __syncthreads();
  // p3: F=128, K=256; (ntile = w&3, mq = w>>2)
  { int mq = w >> 2;
    if (mq < 3) proj_part<16,8,SAB,1,false>(aB, wsp + 98304, 256, b3, hT, w&3, mq, lane);
    else        proj_part<16,8,SAB,0,true >(aB, wsp + 98304, 256, b3, hT, w&3, 0, lane);
  }
  __syncthreads();
  // a4: F=128; (ftile = w&3, nq = w>>2)
  { int nq = w >> 2;
    if (nq < 3) agg_part<1,false>(hT, Xs, aB, w&3, nq, lane);
    else        agg_part<0,true >(hT, Xs, aB, w&3, 0, lane);
  }
  __syncthreads();
  // p4: F=64, K=128; (ntile = w&1, mq = w>>1), waves >=8 idle
  { int mq = w >> 1;
    if (mq < 3)      proj_part<8,4,SAB,1,false>(aB, wsp + 131072, 128, b4, hT, w&1, mq, lane);
    else if (mq == 3) proj_part<8,4,SAB,0,true>(aB, wsp + 131072, 128, b4, hT, w&1, 0, lane);
  }
  __syncthreads();
  // a5: F=64; (ftile = w&1, nq = w>>1), waves >=8 idle
  { int nq = w >> 1;
    if (nq < 3)      agg_part<1,false>(hT, Xs, aB, w&1, nq, lane);
    else if (nq == 3) agg_part<0,true>(hT, Xs, aB, w&1, 0, lane);
  }
  __syncthreads();

  // final: h5[n] = relu(b5 + a5[n][:].W5); out = bf + sum_n h5[n]*Wf[n]
  float partial = 0.f;
  if (tid < NODE) {
    const ushort_t* row = aB + tid*SAB;
    float s = 0.f;
    #pragma unroll
    for (int k4 = 0; k4 < 16; k4++) {
      uint2 u = *(const uint2*)(row + k4*4);
      s += bf2f((ushort_t)(u.x & 0xFFFF)) * W5[k4*4+0];
      s += bf2f((ushort_t)(u.x >> 16))    * W5[k4*4+1];
      s += bf2f((ushort_t)(u.y & 0xFFFF)) * W5[k4*4+2];
      s += bf2f((ushort_t)(u.y >> 16))    * W5[k4*4+3];
    }
    s += b5[0];
    s = s > 0.f ? s : 0.f;
    partial = s * Wf[tid];
  }
  float* red = (float*)Xs;               // Xs dead after a5
  if (tid < 128) red[tid] = partial;     // lanes 112..127 write 0
  __syncthreads();
  if (w == 0) {
    float v = red[lane] + red[lane + 64];
    #pragma unroll
    for (int off = 32; off > 0; off >>= 1)
      v += __shfl_xor(v, off, 64);
    if (lane == 0) out[blockIdx.x] = v + bfc[0];
  }
}

extern "C" void kernel_launch(void* const* d_in, const int* in_sizes, int n_in,
                              void* d_out, int out_size, void* d_ws, size_t ws_size,
                              hipStream_t stream) {
  const float* x   = (const float*)d_in[0];
  const float* W1  = (const float*)d_in[1];
  const float* b1  = (const float*)d_in[2];
  const float* W2  = (const float*)d_in[3];
  const float* b2  = (const float*)d_in[4];
  const float* W3  = (const float*)d_in[5];
  const float* b3  = (const float*)d_in[6];
  const float* W4  = (const float*)d_in[7];
  const float* b4  = (const float*)d_in[8];
  const float* W5  = (const float*)d_in[9];
  const float* b5  = (const float*)d_in[10];
  const float* Wf  = (const float*)d_in[11];
  const float* bfc = (const float*)d_in[12];
  ushort_t* wsp = (ushort_t*)d_ws;
  float* out = (float*)d_out;

  prep_weights<<<544, 256, 0, stream>>>(W1, W2, W3, W4, wsp);

  (void)hipFuncSetAttribute((const void*)gcn_kernel,
                            hipFuncAttributeMaxDynamicSharedMemorySize, SMEM_BYTES);
  gcn_kernel<<<NBATCH, 1024, SMEM_BYTES, stream>>>(x, wsp, b1, b2, b3, b4,
                                                   W5, b5, Wf, bfc, out);
}